// Round 1
// baseline (2663.052 us; speedup 1.0000x reference)
//
#include <hip/hip_runtime.h>

namespace {

constexpr int N   = 100000;
constexpr int E   = 600000;
constexpr int B   = 50;
constexpr int F   = 40;
constexpr int TF  = B * F;     // 2000
constexpr int D0  = 64;
constexpr int H   = 128;
constexpr int C   = 2;

// ---------------- histograms / CSR build ----------------

__global__ void hist_edges(const int* __restrict__ dst, int* __restrict__ deg) {
  int e = blockIdx.x * 256 + threadIdx.x;
  if (e < E) atomicAdd(&deg[dst[e]], 1);
}

__global__ void hist_nodes(const int* __restrict__ b0, const int* __restrict__ a0l,
                           int* __restrict__ cnt1, int* __restrict__ cntB,
                           int* __restrict__ assign0) {
  int i = blockIdx.x * 256 + threadIdx.x;
  if (i < N) {
    int g = b0[i];
    int a = g * F + a0l[i];
    assign0[i] = a;
    atomicAdd(&cnt1[a], 1);
    atomicAdd(&cntB[g], 1);
  }
}

__global__ void scan1(const int* __restrict__ cnt, int* __restrict__ offs,
                      int* __restrict__ part) {
  __shared__ int lds[256];
  int t = threadIdx.x;
  int base = blockIdx.x * 1024 + t * 4;
  int v[4];
#pragma unroll
  for (int j = 0; j < 4; ++j) v[j] = (base + j < N) ? cnt[base + j] : 0;
  int s = v[0] + v[1] + v[2] + v[3];
  lds[t] = s;
  __syncthreads();
  for (int off = 1; off < 256; off <<= 1) {
    int x = (t >= off) ? lds[t - off] : 0;
    __syncthreads();
    lds[t] += x;
    __syncthreads();
  }
  int ex = lds[t] - s;
  if (t == 255) part[blockIdx.x] = lds[255];
  int run = ex;
#pragma unroll
  for (int j = 0; j < 4; ++j) {
    if (base + j < N) offs[base + j] = run;
    run += v[j];
  }
}

__global__ void scan2(const int* __restrict__ part, int* __restrict__ partEx, int nb) {
  __shared__ int lds[128];
  int t = threadIdx.x;
  int s = (t < nb) ? part[t] : 0;
  lds[t] = s;
  __syncthreads();
  for (int off = 1; off < 128; off <<= 1) {
    int x = (t >= off) ? lds[t - off] : 0;
    __syncthreads();
    lds[t] += x;
    __syncthreads();
  }
  partEx[t] = lds[t] - s;
}

__global__ void scan3(int* __restrict__ offs, const int* __restrict__ partEx,
                      const int* __restrict__ deg, float* __restrict__ rdeg,
                      const int* __restrict__ cnt1, float* __restrict__ rdeg1,
                      const int* __restrict__ cntB, float* __restrict__ rdegB,
                      int* __restrict__ assign1) {
  int i = blockIdx.x * 256 + threadIdx.x;
  if (i < N) {
    offs[i] += partEx[i >> 10];
    rdeg[i] = 1.0f / fmaxf((float)deg[i], 1.0f);
    if (i == 0) offs[N] = E;
    if (i < TF) { rdeg1[i] = 1.0f / fmaxf((float)cnt1[i], 1.0f); assign1[i] = i / F; }
    if (i < B) rdegB[i] = 1.0f / fmaxf((float)cntB[i], 1.0f);
  }
}

__global__ void scatter_k(const int* __restrict__ src, const int* __restrict__ dst,
                          const int* __restrict__ offs, int* __restrict__ cursor,
                          int* __restrict__ srcS) {
  int e = blockIdx.x * 256 + threadIdx.x;
  if (e < E) {
    int d = dst[e];
    int pos = offs[d] + atomicAdd(&cursor[d], 1);
    srcS[pos] = src[e];
  }
}

// ---------------- edge aggregation: mean over incoming src rows ----------------
// one wave per dst node; lane covers 2 columns (float2)
__global__ void agg_k(const float* __restrict__ h, const int* __restrict__ offs,
                      const int* __restrict__ srcS, const float* __restrict__ rdeg,
                      float* __restrict__ out) {
  int wid = blockIdx.x * 4 + (threadIdx.x >> 6);
  int lane = threadIdx.x & 63;
  if (wid >= N) return;
  int o0 = offs[wid], o1 = offs[wid + 1];
  float ax = 0.f, ay = 0.f;
  for (int e = o0; e < o1; ++e) {
    int s = srcS[e];
    float2 v = ((const float2*)(h + (size_t)s * H))[lane];
    ax += v.x; ay += v.y;
  }
  float sc = rdeg[wid];
  float2 r; r.x = ax * sc; r.y = ay * sc;
  ((float2*)(out + (size_t)wid * H))[lane] = r;
}

// ---------------- generic fused fp32 GEMM ----------------
// out[i][:] = (relu?)( A[i,:]@W1 + [Agg[i,:]*(scale?)]@W2 + Gt[Gidx[i],:] + bias )
// tile 128 rows x 128 cols, block 256 threads, 8x8 micro-tile, K-chunks of 16
template <int K, bool AGG, bool GATH, bool RELU, bool SCALE>
__global__ __launch_bounds__(256)
void gemm_k(const float* __restrict__ A, const float* __restrict__ W1,
            const float* __restrict__ Agg, const float* __restrict__ W2,
            const float* __restrict__ ascale,
            const float* __restrict__ Gt, const int* __restrict__ Gidx,
            const float* __restrict__ bias, int hasBias,
            float* __restrict__ out, int n) {
  constexpr int BM = 128, KC = 16;
  __shared__ float As[KC][BM + 4];
  __shared__ float Ws[KC][H + 4];
  const int t = threadIdx.x;
  const int tx = t & 15, ty = t >> 4;
  const int row0 = blockIdx.x * BM;
  float acc[8][8];
#pragma unroll
  for (int r = 0; r < 8; ++r)
#pragma unroll
    for (int c = 0; c < 8; ++c) acc[r][c] = 0.f;

  const int sr = t >> 1;        // staging row 0..127
  const int sk = (t & 1) * 8;   // staging k offset 0/8
  const int wk = t >> 4;        // weight k row 0..15
  const int wc = (t & 15) * 8;  // weight col 0..120

  for (int pass = 0; pass < (AGG ? 2 : 1); ++pass) {
    const float* Ain = (AGG && pass) ? Agg : A;
    const float* Win = (AGG && pass) ? W2 : W1;
    for (int k0 = 0; k0 < K; k0 += KC) {
      float4 a0 = make_float4(0, 0, 0, 0), a1 = make_float4(0, 0, 0, 0);
      int r = row0 + sr;
      if (r < n) {
        const float* ap = Ain + (size_t)r * K + k0 + sk;
        a0 = *(const float4*)ap;
        a1 = *(const float4*)(ap + 4);
        if (AGG && SCALE && pass) {
          float sc = ascale[r];
          a0.x *= sc; a0.y *= sc; a0.z *= sc; a0.w *= sc;
          a1.x *= sc; a1.y *= sc; a1.z *= sc; a1.w *= sc;
        }
      }
      const float* wp = Win + (size_t)(k0 + wk) * H + wc;
      float4 w0 = *(const float4*)wp;
      float4 w1 = *(const float4*)(wp + 4);
      __syncthreads();  // previous chunk's LDS reads complete
      As[sk + 0][sr] = a0.x; As[sk + 1][sr] = a0.y;
      As[sk + 2][sr] = a0.z; As[sk + 3][sr] = a0.w;
      As[sk + 4][sr] = a1.x; As[sk + 5][sr] = a1.y;
      As[sk + 6][sr] = a1.z; As[sk + 7][sr] = a1.w;
      *(float4*)&Ws[wk][wc] = w0;
      *(float4*)&Ws[wk][wc + 4] = w1;
      __syncthreads();
#pragma unroll
      for (int k = 0; k < KC; ++k) {
        float4 av0 = *(const float4*)&As[k][ty * 8];
        float4 av1 = *(const float4*)&As[k][ty * 8 + 4];
        float4 bv0 = *(const float4*)&Ws[k][tx * 8];
        float4 bv1 = *(const float4*)&Ws[k][tx * 8 + 4];
        float a_[8] = {av0.x, av0.y, av0.z, av0.w, av1.x, av1.y, av1.z, av1.w};
        float b_[8] = {bv0.x, bv0.y, bv0.z, bv0.w, bv1.x, bv1.y, bv1.z, bv1.w};
#pragma unroll
        for (int rr = 0; rr < 8; ++rr)
#pragma unroll
          for (int cc = 0; cc < 8; ++cc) acc[rr][cc] += a_[rr] * b_[cc];
      }
    }
  }

#pragma unroll
  for (int rr = 0; rr < 8; ++rr) {
    int row = row0 + ty * 8 + rr;
    if (row >= n) continue;
    const float* grow = nullptr;
    if (GATH) grow = Gt + (size_t)Gidx[row] * H;
    float v[8];
#pragma unroll
    for (int cc = 0; cc < 8; ++cc) {
      int col = tx * 8 + cc;
      float x = acc[rr][cc];
      if (hasBias) x += bias[col];
      if (GATH) x += grow[col];
      if (RELU) x = fmaxf(x, 0.f);
      v[cc] = x;
    }
    float* op = out + (size_t)row * H + tx * 8;
    *(float4*)op = make_float4(v[0], v[1], v[2], v[3]);
    *(float4*)(op + 4) = make_float4(v[4], v[5], v[6], v[7]);
  }
}

// ---------------- pooling ----------------
// node->function sums: 400 blocks (250 rows each), LDS column-partitioned acc
__global__ void pool_p01(const float* __restrict__ h0, const int* __restrict__ a0l,
                         const int* __restrict__ b0, float* __restrict__ p01s) {
  __shared__ float acc[F][H];
  int t = threadIdx.x;  // 128
#pragma unroll
  for (int f = 0; f < F; ++f) acc[f][t] = 0.f;
  int rowbase = blockIdx.x * 250;
  for (int i = 0; i < 250; ++i) {
    int r = rowbase + i;
    acc[a0l[r]][t] += h0[(size_t)r * H + t];
  }
  int g = b0[rowbase];
#pragma unroll
  for (int f = 0; f < F; ++f)
    atomicAdd(&p01s[((size_t)(g * F + f)) * H + t], acc[f][t]);
}

__global__ void pool_g0(const float* __restrict__ h0, const int* __restrict__ b0,
                        float* __restrict__ g0s) {
  int t = threadIdx.x;
  int rowbase = blockIdx.x * 250;
  float a = 0.f;
  for (int i = 0; i < 250; ++i) a += h0[(size_t)(rowbase + i) * H + t];
  atomicAdd(&g0s[(size_t)b0[rowbase] * H + t], a);
}

// mean over F contiguous rows per graph (assign1 = i//F is contiguous)
__global__ void mean40(const float* __restrict__ hin, float* __restrict__ outp) {
  int t = threadIdx.x, g = blockIdx.x;
  float a = 0.f;
  for (int i = 0; i < F; ++i) a += hin[(size_t)(g * F + i) * H + t];
  outp[(size_t)g * H + t] = a * (1.0f / F);
}

// ---------------- head MLP ----------------
__global__ void head_k(const float* __restrict__ g0s, const float* __restrict__ rdegB,
                       const float* __restrict__ g1, const float* __restrict__ h2,
                       const float* __restrict__ W1h, const float* __restrict__ b1h,
                       const float* __restrict__ W2h, const float* __restrict__ b2h,
                       float* __restrict__ out) {
  __shared__ float gv[3 * H];
  __shared__ float z[H];
  int b = blockIdx.x, t = threadIdx.x;
  gv[t] = g0s[(size_t)b * H + t] * rdegB[b];
  gv[H + t] = g1[(size_t)b * H + t];
  gv[2 * H + t] = h2[(size_t)b * H + t];
  __syncthreads();
  float s = b1h[t];
  for (int k = 0; k < 3 * H; ++k) s += gv[k] * W1h[k * H + t];
  z[t] = fmaxf(s, 0.f);
  __syncthreads();
  if (t < C) {
    float o = b2h[t];
    for (int k = 0; k < H; ++k) o += z[k] * W2h[k * C + t];
    out[b * C + t] = o;
  }
}

}  // namespace

extern "C" void kernel_launch(void* const* d_in, const int* in_sizes, int n_in,
                              void* d_out, int out_size, void* d_ws, size_t ws_size,
                              hipStream_t stream) {
  (void)in_sizes; (void)n_in; (void)out_size; (void)ws_size;
  const float* x0   = (const float*)d_in[0];
  const int*   ei   = (const int*)d_in[1];
  const int*   src  = ei;
  const int*   dst  = ei + E;
  const int*   b0   = (const int*)d_in[2];
  const int*   a0l  = (const int*)d_in[3];
  const float* Wp   = (const float*)d_in[4];
  const float* bp   = (const float*)d_in[5];
  const float* e0in_Ws = (const float*)d_in[6];
  const float* e0in_Wn = (const float*)d_in[7];
  const float* e0in_b  = (const float*)d_in[8];
  const float* enc0_Ws = (const float*)d_in[9];
  const float* enc0_Wn = (const float*)d_in[10];
  const float* enc0_b  = (const float*)d_in[11];
  const float* e1in_Ws = (const float*)d_in[12];
  const float* e1in_b  = (const float*)d_in[13];
  const float* e2in_Ws = (const float*)d_in[14];
  const float* e2in_b  = (const float*)d_in[15];
  const float* enc1_Ws = (const float*)d_in[16];
  const float* enc1_b  = (const float*)d_in[17];
  const float* enc2_Ws = (const float*)d_in[18];
  const float* enc2_b  = (const float*)d_in[19];
  const float* A0 = (const float*)d_in[20];
  const float* A1 = (const float*)d_in[21];
  const float* A2 = (const float*)d_in[22];
  const float* U0 = (const float*)d_in[23];
  const float* U1 = (const float*)d_in[24];
  const float* D1 = (const float*)d_in[25];
  const float* D2 = (const float*)d_in[26];
  const float* ib0 = (const float*)d_in[27];
  const float* ib1 = (const float*)d_in[28];
  const float* ib2 = (const float*)d_in[29];
  const float* H1w = (const float*)d_in[30];
  const float* hb1 = (const float*)d_in[31];
  const float* H2w = (const float*)d_in[32];
  const float* hb2 = (const float*)d_in[33];
  float* out = (float*)d_out;

  // ---- workspace carve ----
  char* p = (char*)d_ws;
  auto carve = [&](size_t bytes) {
    char* r = p;
    p += (bytes + 255) & ~(size_t)255;
    return r;
  };
  char* z0 = p;  // zeroed-every-call region
  int*   deg    = (int*)carve((size_t)N * 4);
  int*   cursor = (int*)carve((size_t)N * 4);
  int*   cnt1   = (int*)carve((size_t)TF * 4);
  int*   cntB   = (int*)carve(64 * 4);
  float* h1a    = (float*)carve((size_t)TF * H * 4);
  float* h2a    = (float*)carve((size_t)B * H * 4);
  float* g0s    = (float*)carve((size_t)B * H * 4);
  size_t zbytes = (size_t)(p - z0);
  float* h0   = (float*)carve((size_t)N * H * 4);
  float* agg  = (float*)carve((size_t)N * H * 4);
  float* h1b  = (float*)carve((size_t)TF * H * 4);
  float* h1d  = (float*)carve((size_t)TF * H * 4);
  float* p01s = (float*)carve((size_t)TF * H * 4);
  float* h2b  = (float*)carve((size_t)B * H * 4);
  float* h2d  = (float*)carve((size_t)B * H * 4);
  float* p12  = (float*)carve((size_t)B * H * 4);
  float* g1   = (float*)carve((size_t)B * H * 4);
  float* rdeg = (float*)carve((size_t)N * 4);
  float* rdeg1 = (float*)carve((size_t)TF * 4);
  float* rdegB = (float*)carve(64 * 4);
  int* offs    = (int*)carve((size_t)(N + 64) * 4);
  int* srcS    = (int*)carve((size_t)E * 4);
  int* part    = (int*)carve(128 * 4);
  int* partEx  = (int*)carve(128 * 4);
  int* assign0 = (int*)carve((size_t)N * 4);
  int* assign1 = (int*)carve((size_t)TF * 4);

  auto gemmGrid = [](int n) { return (n + 127) / 128; };
  const int HH = H * H;

  // ---- CSR + histograms ----
  hipMemsetAsync(z0, 0, zbytes, stream);
  hist_edges<<<(E + 255) / 256, 256, 0, stream>>>(dst, deg);
  hist_nodes<<<(N + 255) / 256, 256, 0, stream>>>(b0, a0l, cnt1, cntB, assign0);
  const int nb1 = (N + 1023) / 1024;
  scan1<<<nb1, 256, 0, stream>>>(deg, offs, part);
  scan2<<<1, 128, 0, stream>>>(part, partEx, nb1);
  scan3<<<(N + 255) / 256, 256, 0, stream>>>(offs, partEx, deg, rdeg, cnt1, rdeg1,
                                             cntB, rdegB, assign1);
  scatter_k<<<(E + 255) / 256, 256, 0, stream>>>(src, dst, offs, cursor, srcS);

  // ---- input projection ----
  gemm_k<D0, false, false, true, false><<<gemmGrid(N), 256, 0, stream>>>(
      x0, Wp, nullptr, nullptr, nullptr, nullptr, nullptr, bp, 1, h0, N);

  auto encEdge = [&](const float* Wsarr, const float* Wnarr, const float* barr) {
    for (int l = 0; l < 2; ++l) {
      agg_k<<<N / 4, 256, 0, stream>>>(h0, offs, srcS, rdeg, agg);
      gemm_k<H, true, false, true, false><<<gemmGrid(N), 256, 0, stream>>>(
          h0, Wsarr + l * HH, agg, Wnarr + l * HH, nullptr, nullptr, nullptr,
          barr + l * H, 1, h0, N);
    }
  };
  auto encPlain = [&](float* cur, float* alt, const float* Wsarr, const float* barr,
                      int n) {
    gemm_k<H, false, false, true, false><<<gemmGrid(n), 256, 0, stream>>>(
        cur, Wsarr, nullptr, nullptr, nullptr, nullptr, nullptr, barr, 1, alt, n);
    gemm_k<H, false, false, true, false><<<gemmGrid(n), 256, 0, stream>>>(
        alt, Wsarr + HH, nullptr, nullptr, nullptr, nullptr, nullptr, barr + H, 1,
        cur, n);
  };

  encEdge(e0in_Ws, e0in_Wn, e0in_b);
  float* h1cur = h1a; float* h1alt = h1b;
  float* h2cur = h2a; float* h2alt = h2b;
  encPlain(h1cur, h1alt, e1in_Ws, e1in_b, TF);   // h1a was zeroed
  encPlain(h2cur, h2alt, e2in_Ws, e2in_b, B);    // h2a was zeroed

  for (int step = 0; step < 2; ++step) {
    hipMemsetAsync(p01s, 0, (size_t)TF * H * 4, stream);
    pool_p01<<<400, 128, 0, stream>>>(h0, a0l, b0, p01s);
    mean40<<<B, 128, 0, stream>>>(h1cur, p12);
    gemm_k<H, false, false, false, false><<<gemmGrid(TF), 256, 0, stream>>>(
        h1cur, D1, nullptr, nullptr, nullptr, nullptr, nullptr, nullptr, 0, h1d, TF);
    gemm_k<H, false, false, false, false><<<gemmGrid(B), 256, 0, stream>>>(
        h2cur, D2, nullptr, nullptr, nullptr, nullptr, nullptr, nullptr, 0, h2d, B);
    // n0 = relu(h0@A0 + (h1@D1)[assign0] + ib0)   (in-place on h0)
    gemm_k<H, false, true, true, false><<<gemmGrid(N), 256, 0, stream>>>(
        h0, A0, nullptr, nullptr, nullptr, h1d, assign0, ib0, 1, h0, N);
    // n1 = relu(h1@A1 + mean_p01@U0 + (h2@D2)[assign1] + ib1)
    gemm_k<H, true, true, true, true><<<gemmGrid(TF), 256, 0, stream>>>(
        h1cur, A1, p01s, U0, rdeg1, h2d, assign1, ib1, 1, h1alt, TF);
    // n2 = relu(h2@A2 + p12@U1 + ib2)
    gemm_k<H, true, false, true, false><<<gemmGrid(B), 256, 0, stream>>>(
        h2cur, A2, p12, U1, nullptr, nullptr, nullptr, ib2, 1, h2alt, B);
    { float* tsw = h1cur; h1cur = h1alt; h1alt = tsw; }
    { float* tsw = h2cur; h2cur = h2alt; h2alt = tsw; }
    encEdge(enc0_Ws, enc0_Wn, enc0_b);
    encPlain(h1cur, h1alt, enc1_Ws, enc1_b, TF);
    encPlain(h2cur, h2alt, enc2_Ws, enc2_b, B);
  }

  pool_g0<<<400, 128, 0, stream>>>(h0, b0, g0s);
  mean40<<<B, 128, 0, stream>>>(h1cur, g1);
  head_k<<<B, 128, 0, stream>>>(g0s, rdegB, g1, h2cur, H1w, hb1, H2w, hb2, out);
}

// Round 2
// 2102.066 us; speedup vs baseline: 1.2669x; 1.2669x over previous
//
#include <hip/hip_runtime.h>

namespace {

constexpr int N   = 100000;
constexpr int E   = 600000;
constexpr int B   = 50;
constexpr int F   = 40;
constexpr int TF  = B * F;     // 2000
constexpr int D0  = 64;
constexpr int H   = 128;
constexpr int C   = 2;

// ---------------- histograms / CSR build ----------------

__global__ void hist_edges(const int* __restrict__ dst, int* __restrict__ deg) {
  int e = blockIdx.x * 256 + threadIdx.x;
  if (e < E) atomicAdd(&deg[dst[e]], 1);
}

// LDS histogram: avoids L2 same-address atomic serialization (was 575 us with
// direct global atomics: all lanes share one graph id -> 2 cache lines).
__global__ void hist_nodes(const int* __restrict__ b0, const int* __restrict__ a0l,
                           int* __restrict__ cnt1, int* __restrict__ assign0) {
  __shared__ int lh[TF];
  int t = threadIdx.x;
  for (int j = t; j < TF; j += 256) lh[j] = 0;
  __syncthreads();
  int i = blockIdx.x * 256 + t;
  if (i < N) {
    int g = b0[i];
    int a = g * F + a0l[i];
    assign0[i] = a;
    atomicAdd(&lh[a], 1);
  }
  __syncthreads();
  for (int j = t; j < TF; j += 256) {
    int c = lh[j];
    if (c) atomicAdd(&cnt1[j], c);
  }
}

__global__ void scan1(const int* __restrict__ cnt, int* __restrict__ offs,
                      int* __restrict__ part) {
  __shared__ int lds[256];
  int t = threadIdx.x;
  int base = blockIdx.x * 1024 + t * 4;
  int v[4];
#pragma unroll
  for (int j = 0; j < 4; ++j) v[j] = (base + j < N) ? cnt[base + j] : 0;
  int s = v[0] + v[1] + v[2] + v[3];
  lds[t] = s;
  __syncthreads();
  for (int off = 1; off < 256; off <<= 1) {
    int x = (t >= off) ? lds[t - off] : 0;
    __syncthreads();
    lds[t] += x;
    __syncthreads();
  }
  int ex = lds[t] - s;
  if (t == 255) part[blockIdx.x] = lds[255];
  int run = ex;
#pragma unroll
  for (int j = 0; j < 4; ++j) {
    if (base + j < N) offs[base + j] = run;
    run += v[j];
  }
}

__global__ void scan2(const int* __restrict__ part, int* __restrict__ partEx, int nb) {
  __shared__ int lds[128];
  int t = threadIdx.x;
  int s = (t < nb) ? part[t] : 0;
  lds[t] = s;
  __syncthreads();
  for (int off = 1; off < 128; off <<= 1) {
    int x = (t >= off) ? lds[t - off] : 0;
    __syncthreads();
    lds[t] += x;
    __syncthreads();
  }
  partEx[t] = lds[t] - s;
}

__global__ void scan3(int* __restrict__ offs, const int* __restrict__ partEx,
                      const int* __restrict__ deg, float* __restrict__ rdeg,
                      const int* __restrict__ cnt1, float* __restrict__ rdeg1,
                      float* __restrict__ rdegB, int* __restrict__ assign1) {
  int i = blockIdx.x * 256 + threadIdx.x;
  if (i < N) {
    offs[i] += partEx[i >> 10];
    rdeg[i] = 1.0f / fmaxf((float)deg[i], 1.0f);
    if (i == 0) offs[N] = E;
    if (i < TF) { rdeg1[i] = 1.0f / fmaxf((float)cnt1[i], 1.0f); assign1[i] = i / F; }
    if (i < B) {
      int s = 0;
      for (int f = 0; f < F; ++f) s += cnt1[i * F + f];
      rdegB[i] = 1.0f / fmaxf((float)s, 1.0f);
    }
  }
}

__global__ void scatter_k(const int* __restrict__ src, const int* __restrict__ dst,
                          const int* __restrict__ offs, int* __restrict__ cursor,
                          int* __restrict__ srcS) {
  int e = blockIdx.x * 256 + threadIdx.x;
  if (e < E) {
    int d = dst[e];
    int pos = offs[d] + atomicAdd(&cursor[d], 1);
    srcS[pos] = src[e];
  }
}

// ---------------- edge aggregation: mean over incoming src rows ----------------
// one wave per dst node; lane covers 2 columns (float2)
__global__ void agg_k(const float* __restrict__ h, const int* __restrict__ offs,
                      const int* __restrict__ srcS, const float* __restrict__ rdeg,
                      float* __restrict__ out) {
  int wid = blockIdx.x * 4 + (threadIdx.x >> 6);
  int lane = threadIdx.x & 63;
  if (wid >= N) return;
  int o0 = offs[wid], o1 = offs[wid + 1];
  float ax = 0.f, ay = 0.f;
  for (int e = o0; e < o1; ++e) {
    int s = srcS[e];
    float2 v = ((const float2*)(h + (size_t)s * H))[lane];
    ax += v.x; ay += v.y;
  }
  float sc = rdeg[wid];
  float2 r; r.x = ax * sc; r.y = ay * sc;
  ((float2*)(out + (size_t)wid * H))[lane] = r;
}

// ---------------- generic fused fp32 GEMM ----------------
// out[i][:] = (relu?)( A[i,:]@W1 + [Agg[i,:]*(scale?)]@W2 + Gt[Gidx[i],:] + bias )
// tile 128 rows x 128 cols, block 256 threads, 8x8 micro-tile, K-chunks of 16
template <int K, bool AGG, bool GATH, bool RELU, bool SCALE>
__global__ __launch_bounds__(256)
void gemm_k(const float* __restrict__ A, const float* __restrict__ W1,
            const float* __restrict__ Agg, const float* __restrict__ W2,
            const float* __restrict__ ascale,
            const float* __restrict__ Gt, const int* __restrict__ Gidx,
            const float* __restrict__ bias, int hasBias,
            float* __restrict__ out, int n) {
  constexpr int BM = 128, KC = 16;
  __shared__ float As[KC][BM + 4];
  __shared__ float Ws[KC][H + 4];
  const int t = threadIdx.x;
  const int tx = t & 15, ty = t >> 4;
  const int row0 = blockIdx.x * BM;
  float acc[8][8];
#pragma unroll
  for (int r = 0; r < 8; ++r)
#pragma unroll
    for (int c = 0; c < 8; ++c) acc[r][c] = 0.f;

  const int sr = t >> 1;        // staging row 0..127
  const int sk = (t & 1) * 8;   // staging k offset 0/8
  const int wk = t >> 4;        // weight k row 0..15
  const int wc = (t & 15) * 8;  // weight col 0..120

  for (int pass = 0; pass < (AGG ? 2 : 1); ++pass) {
    const float* Ain = (AGG && pass) ? Agg : A;
    const float* Win = (AGG && pass) ? W2 : W1;
    for (int k0 = 0; k0 < K; k0 += KC) {
      float4 a0 = make_float4(0, 0, 0, 0), a1 = make_float4(0, 0, 0, 0);
      int r = row0 + sr;
      if (r < n) {
        const float* ap = Ain + (size_t)r * K + k0 + sk;
        a0 = *(const float4*)ap;
        a1 = *(const float4*)(ap + 4);
        if (AGG && SCALE && pass) {
          float sc = ascale[r];
          a0.x *= sc; a0.y *= sc; a0.z *= sc; a0.w *= sc;
          a1.x *= sc; a1.y *= sc; a1.z *= sc; a1.w *= sc;
        }
      }
      const float* wp = Win + (size_t)(k0 + wk) * H + wc;
      float4 w0 = *(const float4*)wp;
      float4 w1 = *(const float4*)(wp + 4);
      __syncthreads();  // previous chunk's LDS reads complete
      As[sk + 0][sr] = a0.x; As[sk + 1][sr] = a0.y;
      As[sk + 2][sr] = a0.z; As[sk + 3][sr] = a0.w;
      As[sk + 4][sr] = a1.x; As[sk + 5][sr] = a1.y;
      As[sk + 6][sr] = a1.z; As[sk + 7][sr] = a1.w;
      *(float4*)&Ws[wk][wc] = w0;
      *(float4*)&Ws[wk][wc + 4] = w1;
      __syncthreads();
#pragma unroll
      for (int k = 0; k < KC; ++k) {
        float4 av0 = *(const float4*)&As[k][ty * 8];
        float4 av1 = *(const float4*)&As[k][ty * 8 + 4];
        float4 bv0 = *(const float4*)&Ws[k][tx * 8];
        float4 bv1 = *(const float4*)&Ws[k][tx * 8 + 4];
        float a_[8] = {av0.x, av0.y, av0.z, av0.w, av1.x, av1.y, av1.z, av1.w};
        float b_[8] = {bv0.x, bv0.y, bv0.z, bv0.w, bv1.x, bv1.y, bv1.z, bv1.w};
#pragma unroll
        for (int rr = 0; rr < 8; ++rr)
#pragma unroll
          for (int cc = 0; cc < 8; ++cc) acc[rr][cc] += a_[rr] * b_[cc];
      }
    }
  }

#pragma unroll
  for (int rr = 0; rr < 8; ++rr) {
    int row = row0 + ty * 8 + rr;
    if (row >= n) continue;
    const float* grow = nullptr;
    if (GATH) grow = Gt + (size_t)Gidx[row] * H;
    float v[8];
#pragma unroll
    for (int cc = 0; cc < 8; ++cc) {
      int col = tx * 8 + cc;
      float x = acc[rr][cc];
      if (hasBias) x += bias[col];
      if (GATH) x += grow[col];
      if (RELU) x = fmaxf(x, 0.f);
      v[cc] = x;
    }
    float* op = out + (size_t)row * H + tx * 8;
    *(float4*)op = make_float4(v[0], v[1], v[2], v[3]);
    *(float4*)(op + 4) = make_float4(v[4], v[5], v[6], v[7]);
  }
}

// ---------------- pooling ----------------
// node->function sums: 400 blocks (250 rows each), LDS column-partitioned acc
__global__ void pool_p01(const float* __restrict__ h0, const int* __restrict__ a0l,
                         const int* __restrict__ b0, float* __restrict__ p01s) {
  __shared__ float acc[F][H];
  int t = threadIdx.x;  // 128
#pragma unroll
  for (int f = 0; f < F; ++f) acc[f][t] = 0.f;
  int rowbase = blockIdx.x * 250;
  for (int i = 0; i < 250; ++i) {
    int r = rowbase + i;
    acc[a0l[r]][t] += h0[(size_t)r * H + t];
  }
  int g = b0[rowbase];
#pragma unroll
  for (int f = 0; f < F; ++f)
    atomicAdd(&p01s[((size_t)(g * F + f)) * H + t], acc[f][t]);
}

__global__ void pool_g0(const float* __restrict__ h0, const int* __restrict__ b0,
                        float* __restrict__ g0s) {
  int t = threadIdx.x;
  int rowbase = blockIdx.x * 250;
  float a = 0.f;
  for (int i = 0; i < 250; ++i) a += h0[(size_t)(rowbase + i) * H + t];
  atomicAdd(&g0s[(size_t)b0[rowbase] * H + t], a);
}

// mean over F contiguous rows per graph (assign1 = i//F is contiguous)
__global__ void mean40(const float* __restrict__ hin, float* __restrict__ outp) {
  int t = threadIdx.x, g = blockIdx.x;
  float a = 0.f;
  for (int i = 0; i < F; ++i) a += hin[(size_t)(g * F + i) * H + t];
  outp[(size_t)g * H + t] = a * (1.0f / F);
}

// ---------------- head MLP ----------------
__global__ void head_k(const float* __restrict__ g0s, const float* __restrict__ rdegB,
                       const float* __restrict__ g1, const float* __restrict__ h2,
                       const float* __restrict__ W1h, const float* __restrict__ b1h,
                       const float* __restrict__ W2h, const float* __restrict__ b2h,
                       float* __restrict__ out) {
  __shared__ float gv[3 * H];
  __shared__ float z[H];
  int b = blockIdx.x, t = threadIdx.x;
  gv[t] = g0s[(size_t)b * H + t] * rdegB[b];
  gv[H + t] = g1[(size_t)b * H + t];
  gv[2 * H + t] = h2[(size_t)b * H + t];
  __syncthreads();
  float s = b1h[t];
  for (int k = 0; k < 3 * H; ++k) s += gv[k] * W1h[k * H + t];
  z[t] = fmaxf(s, 0.f);
  __syncthreads();
  if (t < C) {
    float o = b2h[t];
    for (int k = 0; k < H; ++k) o += z[k] * W2h[k * C + t];
    out[b * C + t] = o;
  }
}

}  // namespace

extern "C" void kernel_launch(void* const* d_in, const int* in_sizes, int n_in,
                              void* d_out, int out_size, void* d_ws, size_t ws_size,
                              hipStream_t stream) {
  (void)in_sizes; (void)n_in; (void)out_size; (void)ws_size;
  const float* x0   = (const float*)d_in[0];
  const int*   ei   = (const int*)d_in[1];
  const int*   src  = ei;
  const int*   dst  = ei + E;
  const int*   b0   = (const int*)d_in[2];
  const int*   a0l  = (const int*)d_in[3];
  const float* Wp   = (const float*)d_in[4];
  const float* bp   = (const float*)d_in[5];
  const float* e0in_Ws = (const float*)d_in[6];
  const float* e0in_Wn = (const float*)d_in[7];
  const float* e0in_b  = (const float*)d_in[8];
  const float* enc0_Ws = (const float*)d_in[9];
  const float* enc0_Wn = (const float*)d_in[10];
  const float* enc0_b  = (const float*)d_in[11];
  const float* e1in_Ws = (const float*)d_in[12];
  const float* e1in_b  = (const float*)d_in[13];
  const float* e2in_Ws = (const float*)d_in[14];
  const float* e2in_b  = (const float*)d_in[15];
  const float* enc1_Ws = (const float*)d_in[16];
  const float* enc1_b  = (const float*)d_in[17];
  const float* enc2_Ws = (const float*)d_in[18];
  const float* enc2_b  = (const float*)d_in[19];
  const float* A0 = (const float*)d_in[20];
  const float* A1 = (const float*)d_in[21];
  const float* A2 = (const float*)d_in[22];
  const float* U0 = (const float*)d_in[23];
  const float* U1 = (const float*)d_in[24];
  const float* D1 = (const float*)d_in[25];
  const float* D2 = (const float*)d_in[26];
  const float* ib0 = (const float*)d_in[27];
  const float* ib1 = (const float*)d_in[28];
  const float* ib2 = (const float*)d_in[29];
  const float* H1w = (const float*)d_in[30];
  const float* hb1 = (const float*)d_in[31];
  const float* H2w = (const float*)d_in[32];
  const float* hb2 = (const float*)d_in[33];
  float* out = (float*)d_out;

  // ---- workspace carve ----
  char* p = (char*)d_ws;
  auto carve = [&](size_t bytes) {
    char* r = p;
    p += (bytes + 255) & ~(size_t)255;
    return r;
  };
  char* z0 = p;  // zeroed-every-call region
  int*   deg    = (int*)carve((size_t)N * 4);
  int*   cursor = (int*)carve((size_t)N * 4);
  int*   cnt1   = (int*)carve((size_t)TF * 4);
  float* h1a    = (float*)carve((size_t)TF * H * 4);
  float* h2a    = (float*)carve((size_t)B * H * 4);
  float* g0s    = (float*)carve((size_t)B * H * 4);
  size_t zbytes = (size_t)(p - z0);
  float* h0   = (float*)carve((size_t)N * H * 4);
  float* agg  = (float*)carve((size_t)N * H * 4);
  float* h1b  = (float*)carve((size_t)TF * H * 4);
  float* h1d  = (float*)carve((size_t)TF * H * 4);
  float* p01s = (float*)carve((size_t)TF * H * 4);
  float* h2b  = (float*)carve((size_t)B * H * 4);
  float* h2d  = (float*)carve((size_t)B * H * 4);
  float* p12  = (float*)carve((size_t)B * H * 4);
  float* g1   = (float*)carve((size_t)B * H * 4);
  float* rdeg = (float*)carve((size_t)N * 4);
  float* rdeg1 = (float*)carve((size_t)TF * 4);
  float* rdegB = (float*)carve(64 * 4);
  int* offs    = (int*)carve((size_t)(N + 64) * 4);
  int* srcS    = (int*)carve((size_t)E * 4);
  int* part    = (int*)carve(128 * 4);
  int* partEx  = (int*)carve(128 * 4);
  int* assign0 = (int*)carve((size_t)N * 4);
  int* assign1 = (int*)carve((size_t)TF * 4);

  auto gemmGrid = [](int n) { return (n + 127) / 128; };
  const int HH = H * H;

  // ---- CSR + histograms ----
  hipMemsetAsync(z0, 0, zbytes, stream);
  hist_edges<<<(E + 255) / 256, 256, 0, stream>>>(dst, deg);
  hist_nodes<<<(N + 255) / 256, 256, 0, stream>>>(b0, a0l, cnt1, assign0);
  const int nb1 = (N + 1023) / 1024;
  scan1<<<nb1, 256, 0, stream>>>(deg, offs, part);
  scan2<<<1, 128, 0, stream>>>(part, partEx, nb1);
  scan3<<<(N + 255) / 256, 256, 0, stream>>>(offs, partEx, deg, rdeg, cnt1, rdeg1,
                                             rdegB, assign1);
  scatter_k<<<(E + 255) / 256, 256, 0, stream>>>(src, dst, offs, cursor, srcS);

  // ---- input projection ----
  gemm_k<D0, false, false, true, false><<<gemmGrid(N), 256, 0, stream>>>(
      x0, Wp, nullptr, nullptr, nullptr, nullptr, nullptr, bp, 1, h0, N);

  auto encEdge = [&](const float* Wsarr, const float* Wnarr, const float* barr) {
    for (int l = 0; l < 2; ++l) {
      agg_k<<<N / 4, 256, 0, stream>>>(h0, offs, srcS, rdeg, agg);
      gemm_k<H, true, false, true, false><<<gemmGrid(N), 256, 0, stream>>>(
          h0, Wsarr + l * HH, agg, Wnarr + l * HH, nullptr, nullptr, nullptr,
          barr + l * H, 1, h0, N);
    }
  };
  auto encPlain = [&](float* cur, float* alt, const float* Wsarr, const float* barr,
                      int n) {
    gemm_k<H, false, false, true, false><<<gemmGrid(n), 256, 0, stream>>>(
        cur, Wsarr, nullptr, nullptr, nullptr, nullptr, nullptr, barr, 1, alt, n);
    gemm_k<H, false, false, true, false><<<gemmGrid(n), 256, 0, stream>>>(
        alt, Wsarr + HH, nullptr, nullptr, nullptr, nullptr, nullptr, barr + H, 1,
        cur, n);
  };

  encEdge(e0in_Ws, e0in_Wn, e0in_b);
  float* h1cur = h1a; float* h1alt = h1b;
  float* h2cur = h2a; float* h2alt = h2b;
  encPlain(h1cur, h1alt, e1in_Ws, e1in_b, TF);   // h1a was zeroed
  encPlain(h2cur, h2alt, e2in_Ws, e2in_b, B);    // h2a was zeroed

  for (int step = 0; step < 2; ++step) {
    hipMemsetAsync(p01s, 0, (size_t)TF * H * 4, stream);
    pool_p01<<<400, 128, 0, stream>>>(h0, a0l, b0, p01s);
    mean40<<<B, 128, 0, stream>>>(h1cur, p12);
    gemm_k<H, false, false, false, false><<<gemmGrid(TF), 256, 0, stream>>>(
        h1cur, D1, nullptr, nullptr, nullptr, nullptr, nullptr, nullptr, 0, h1d, TF);
    gemm_k<H, false, false, false, false><<<gemmGrid(B), 256, 0, stream>>>(
        h2cur, D2, nullptr, nullptr, nullptr, nullptr, nullptr, nullptr, 0, h2d, B);
    // n0 = relu(h0@A0 + (h1@D1)[assign0] + ib0)   (in-place on h0)
    gemm_k<H, false, true, true, false><<<gemmGrid(N), 256, 0, stream>>>(
        h0, A0, nullptr, nullptr, nullptr, h1d, assign0, ib0, 1, h0, N);
    // n1 = relu(h1@A1 + mean_p01@U0 + (h2@D2)[assign1] + ib1)
    gemm_k<H, true, true, true, true><<<gemmGrid(TF), 256, 0, stream>>>(
        h1cur, A1, p01s, U0, rdeg1, h2d, assign1, ib1, 1, h1alt, TF);
    // n2 = relu(h2@A2 + p12@U1 + ib2)
    gemm_k<H, true, false, true, false><<<gemmGrid(B), 256, 0, stream>>>(
        h2cur, A2, p12, U1, nullptr, nullptr, nullptr, ib2, 1, h2alt, B);
    { float* tsw = h1cur; h1cur = h1alt; h1alt = tsw; }
    { float* tsw = h2cur; h2cur = h2alt; h2alt = tsw; }
    encEdge(enc0_Ws, enc0_Wn, enc0_b);
    encPlain(h1cur, h1alt, enc1_Ws, enc1_b, TF);
    encPlain(h2cur, h2alt, enc2_Ws, enc2_b, B);
  }

  pool_g0<<<400, 128, 0, stream>>>(h0, b0, g0s);
  mean40<<<B, 128, 0, stream>>>(h1cur, g1);
  head_k<<<B, 128, 0, stream>>>(g0s, rdegB, g1, h2cur, H1w, hb1, H2w, hb2, out);
}